// Round 8
// baseline (343.255 us; speedup 1.0000x reference)
//
#include <hip/hip_runtime.h>
#include <math.h>

#define B 128
#define N 2048
#define D 256
#define K 64
#define CH 16          // chunks per batch in main kernel
#define RPB (N / CH)   // rows per block = 128
#define MASKED_KEY 0x007FFFFFu   // = map(-inf); strictly below every finite-score key

typedef float nfloat4 __attribute__((ext_vector_type(4)));   // native vec for nontemporal builtin

// ---------------- workspace layout (in floats) ----------------
#define OFF_V       0                          // B*D
#define OFF_C2      (OFF_V + B * D)            // B
#define OFF_CNT     (OFF_C2 + B)               // B
#define OFF_KEYS    (OFF_CNT + B)              // B*N uints
#define OFF_PART    (OFF_KEYS + B * N)         // B*CH*D
#define OFF_MODE    (OFF_PART + B * CH * D)    // 64 (aligned pad)
#define OFF_DONE    (OFF_MODE + 64)            // B*16 ints (64B-padded counters)
#define OFF_MHAT    (OFF_DONE + B * 16)        // D*D
#define OFF_U0      (OFF_MHAT + D * D)         // D
#define OFF_W2      (OFF_U0 + D)               // D
#define OFF_CST2    (OFF_W2 + D)               // 1

// ---------------- output layout (in floats) ----------------
#define O_TOK   0                      // B*K*D
#define O_MASK  (O_TOK + B * K * D)    // B*K
#define O_IDX   (O_MASK + B * K)       // B*K
#define O_IMP   (O_IDX + B * K)        // B*K
#define O_GLOB  (O_IMP + B * K)        // B*D

__device__ __forceinline__ bool mask_at(const void* p, int mode, int i) {
    if (mode == 1) return ((const unsigned char*)p)[i] != 0;
    if (mode == 2) return ((const float*)p)[i] != 0.0f;
    return ((const int*)p)[i] != 0;
}

// in-wave inclusive scan (64 lanes)
__device__ __forceinline__ int wave_iscan(int x, int l) {
    #pragma unroll
    for (int d = 1; d < 64; d <<= 1) {
        int y = __shfl_up(x, d, 64);
        if (l >= d) x += y;
    }
    return x;
}

// Batch-independent fold: Mhat = (Wq^T Wk)/16, u0 = (bq^T Wk)/16 + Ws,
// w2 = (Wq^T bk)/16, cst2 = (bq.bk)/16 + bs.  Also zeroes done counters.
__global__ __launch_bounds__(256) void prep0_kernel(
        const float* __restrict__ Wq, const float* __restrict__ bq,
        const float* __restrict__ Wk, const float* __restrict__ bk,
        const float* __restrict__ Ws, const float* __restrict__ bs,
        float* __restrict__ Mhat, float* __restrict__ u0,
        float* __restrict__ w2, float* __restrict__ cst2,
        int* __restrict__ done) {
    int e = blockIdx.x, t = threadIdx.x;
    if (e == 0 && t < B) done[t * 16] = 0;   // per-replay reset (graph-safe)
    __shared__ float col[D];
    col[t] = (e < D) ? Wq[(size_t)t * D + e] : bq[t];
    __syncthreads();
    float acc = 0.f;
    #pragma unroll 8
    for (int r = 0; r < D; ++r) acc = fmaf(col[r], Wk[(size_t)r * D + t], acc);
    if (e < D) Mhat[(size_t)e * D + t] = acc * 0.0625f;
    else       u0[t] = acc * 0.0625f + Ws[t];
    if (t < 64) {
        float p = 0.f;
        #pragma unroll
        for (int j = 0; j < 4; ++j) p = fmaf(col[t + 64 * j], bk[t + 64 * j], p);
        #pragma unroll
        for (int m = 32; m >= 1; m >>= 1) p += __shfl_xor(p, m, 64);
        if (t == 0) {
            if (e < D) w2[e] = p * 0.0625f;
            else       cst2[0] = p * 0.0625f + bs[0];
        }
    }
}

// Per-batch: mode-detect; v_b = ego_b @ Mhat + u0; c2_b = ego_b . w2 + cst2; cnt.
__global__ __launch_bounds__(256) void prep1_kernel(
        const float* __restrict__ latent, const void* __restrict__ maskp,
        const float* __restrict__ Mhat, const float* __restrict__ u0,
        const float* __restrict__ w2, const float* __restrict__ cst2,
        float* __restrict__ v, float* __restrict__ c2, float* __restrict__ cnt,
        int* __restrict__ modep) {
    int b = blockIdx.x, t = threadIdx.x, w = t >> 6, l = t & 63;
    __shared__ float ego[D];
    __shared__ int smode;
    if (w == 0) {
        const unsigned int* mw = (const unsigned int*)maskp;
        bool isF = false, hasHigh = false;
        for (int i = 0; i < 16; ++i) {
            unsigned int x = mw[l * 16 + i];
            if (x == 0x3F800000u) isF = true;
            if (x & 0xFFFFFF00u) hasHigh = true;
        }
        unsigned long long bf = __ballot(isF);
        unsigned long long bh = __ballot(hasHigh);
        if (l == 0) smode = bf ? 2 : (bh ? 1 : 0);
    }
    ego[t] = latent[(size_t)b * N * D + t];
    __syncthreads();
    int mode = smode;
    if (b == 0 && t == 0) *modep = mode;

    float acc = 0.f;
    #pragma unroll 16
    for (int e = 0; e < D; ++e) acc = fmaf(ego[e], Mhat[(size_t)e * D + t], acc);
    v[b * D + t] = acc + u0[t];

    if (t < 64) {
        float p = 0.f;
        #pragma unroll
        for (int j = 0; j < 4; ++j) p = fmaf(ego[t + 64 * j], w2[t + 64 * j], p);
        #pragma unroll
        for (int m = 32; m >= 1; m >>= 1) p += __shfl_xor(p, m, 64);
        if (t == 0) c2[b] = p + cst2[0];
    }
    int local = 0;
    for (int i = 0; i < N / D; ++i) local += mask_at(maskp, mode, b * N + t + D * i) ? 1 : 0;
    __shared__ int ctot;
    if (t == 0) ctot = 0;
    __syncthreads();
    atomicAdd(&ctot, local);
    __syncthreads();
    if (t == 0) cnt[b] = (float)ctot;
}

// Streaming pass + decoupled per-batch epilogue.
// Grid dim3(B, CH): all chunks of a batch share flat%8 -> same XCD (heuristic).
__global__ __launch_bounds__(256, 4) void main_kernel(
        const float* __restrict__ latent, const void* __restrict__ maskp,
        const int* __restrict__ modep,
        const float* __restrict__ v, const float* __restrict__ c2,
        const float* __restrict__ cnt,
        unsigned int* __restrict__ keysg, float* __restrict__ partials,
        int* __restrict__ done,
        float* __restrict__ out_mask, float* __restrict__ out_idx,
        float* __restrict__ out_imp, float* __restrict__ out_tok,
        float* __restrict__ out_glob) {
    int b = blockIdx.x, ch = blockIdx.y;
    int t = threadIdx.x, w = t >> 6, l = t & 63;
    int g = l >> 4, i = l & 15;
    int mode = *modep;

    __shared__ unsigned char smem[16 * D * 4];   // 16 KB, phase-overlaid
    float (*red)[D] = (float(*)[D])smem;
    __shared__ int s_flag;
    __shared__ unsigned int s_byte;
    __shared__ int s_kneed;

    // ---------------- streaming phase ----------------
    const float4* v4 = (const float4*)(v + b * D);
    float4 vv0 = v4[i], vv1 = v4[i + 16], vv2 = v4[i + 32], vv3 = v4[i + 48];
    float c2b = c2[b];
    float4 a0 = {0,0,0,0}, a1 = {0,0,0,0}, a2 = {0,0,0,0}, a3 = {0,0,0,0};
    const nfloat4* lat4 = (const nfloat4*)(latent + (size_t)b * N * D);
    int n0 = ch * RPB + w * (RPB / 4);   // 32 rows per wave
    for (int it = 0; it < RPB / 16; ++it) {
        int n = n0 + it * 4 + g;
        const nfloat4* row = lat4 + (size_t)n * (D / 4);
        nfloat4 x0 = __builtin_nontemporal_load(&row[i]);
        nfloat4 x1 = __builtin_nontemporal_load(&row[i + 16]);
        nfloat4 x2 = __builtin_nontemporal_load(&row[i + 32]);
        nfloat4 x3 = __builtin_nontemporal_load(&row[i + 48]);
        float p = x0.x * vv0.x;
        p = fmaf(x0.y, vv0.y, p); p = fmaf(x0.z, vv0.z, p); p = fmaf(x0.w, vv0.w, p);
        p = fmaf(x1.x, vv1.x, p); p = fmaf(x1.y, vv1.y, p);
        p = fmaf(x1.z, vv1.z, p); p = fmaf(x1.w, vv1.w, p);
        p = fmaf(x2.x, vv2.x, p); p = fmaf(x2.y, vv2.y, p);
        p = fmaf(x2.z, vv2.z, p); p = fmaf(x2.w, vv2.w, p);
        p = fmaf(x3.x, vv3.x, p); p = fmaf(x3.y, vv3.y, p);
        p = fmaf(x3.z, vv3.z, p); p = fmaf(x3.w, vv3.w, p);
        #pragma unroll
        for (int m = 8; m >= 1; m >>= 1) p += __shfl_xor(p, m, 64);  // 16-lane reduce
        bool msk = mask_at(maskp, mode, b * N + n);
        if (i == 0) {
            unsigned int ky = MASKED_KEY;
            if (msk) {
                unsigned int fu = __float_as_uint(p + c2b);
                ky = (fu & 0x80000000u) ? ~fu : (fu | 0x80000000u);
            }
            keysg[(size_t)b * N + n] = ky;
        }
        if (msk) {
            a0.x += x0.x; a0.y += x0.y; a0.z += x0.z; a0.w += x0.w;
            a1.x += x1.x; a1.y += x1.y; a1.z += x1.z; a1.w += x1.w;
            a2.x += x2.x; a2.y += x2.y; a2.z += x2.z; a2.w += x2.w;
            a3.x += x3.x; a3.y += x3.y; a3.z += x3.z; a3.w += x3.w;
        }
    }
    float4* rr = (float4*)red[w * 4 + g];
    rr[i] = a0; rr[i + 16] = a1; rr[i + 32] = a2; rr[i + 48] = a3;
    __syncthreads();
    float s = 0.f;
    #pragma unroll
    for (int r = 0; r < 16; ++r) s += red[r][t];
    partials[((size_t)b * CH + ch) * D + t] = s;

    // ---------------- decoupled completion ----------------
    __threadfence();                        // publish keys/partials device-wide
    if (t == 0) {
        int old = atomicAdd(&done[b * 16], 1);
        s_flag = (old == CH - 1);
    }
    __syncthreads();
    if (!s_flag) return;
    __threadfence();                        // acquire: drop stale lines

    // ---------------- per-batch epilogue (last-arriving block) ----------------
    unsigned int* keys = (unsigned int*)smem;              // 8 KB  (overlays red)
    unsigned int* hist = (unsigned int*)(smem + 8192);     // 1 KB
    unsigned int* selu = (unsigned int*)(smem + 9216);     // 256 B
    int* seliA         = (int*)(smem + 9472);              // 256 B
    int* sortedIdx     = (int*)(smem + 9728);              // 256 B
    int* wtot          = (int*)(smem + 9984);              // 16 B
    int* wtot2         = (int*)(smem + 10000);             // 16 B

    __syncthreads();   // ensure partials-write phase done before overlay reuse
    for (int q = 0; q < N / 256; ++q) {
        int pos = t + 256 * q;
        keys[pos] = keysg[(size_t)b * N + pos];
    }
    __syncthreads();

    // 4-pass radix select with parallel suffix-scan bucket select
    unsigned int prefixKey = 0;
    int kneed = K;
    for (int shift = 24; shift >= 0; shift -= 8) {
        hist[t] = 0;
        __syncthreads();
        for (int q = 0; q < N / 256; ++q) {
            unsigned int u = keys[t * (N / 256) + q];
            bool match = (shift == 24) || ((u >> (shift + 8)) == (prefixKey >> (shift + 8)));
            if (match) atomicAdd(&hist[(u >> shift) & 0xFFu], 1u);
        }
        __syncthreads();
        int h = (int)hist[255 - t];
        int incl = wave_iscan(h, l);
        if (l == 63) wtot[w] = incl;
        __syncthreads();
        int woff = 0;
        #pragma unroll
        for (int ww = 0; ww < 4; ++ww) if (ww < w) woff += wtot[ww];
        incl += woff;
        int excl = incl - h;
        if (incl >= kneed && excl < kneed) {
            s_byte = (unsigned int)(255 - t);
            s_kneed = kneed - excl;
        }
        __syncthreads();
        prefixKey |= (s_byte << shift);
        kneed = s_kneed;
        __syncthreads();
    }
    unsigned int T = prefixKey;

    int cGT = 0, cEQ = 0;
    for (int q = 0; q < N / 256; ++q) {
        unsigned int u = keys[t * (N / 256) + q];
        cGT += (u > T);
        cEQ += (u == T);
    }
    int sGT = wave_iscan(cGT, l);
    int sEQ = wave_iscan(cEQ, l);
    if (l == 63) { wtot[w] = sGT; wtot2[w] = sEQ; }
    __syncthreads();
    int offGT = 0, offEQ = 0, totGT = 0;
    #pragma unroll
    for (int ww = 0; ww < 4; ++ww) {
        if (ww < w) { offGT += wtot[ww]; offEQ += wtot2[ww]; }
        totGT += wtot[ww];
    }
    int pg = sGT - cGT + offGT;
    int pe = sEQ - cEQ + offEQ;
    for (int q = 0; q < N / 256; ++q) {
        int pos = t * (N / 256) + q;
        unsigned int u = keys[pos];
        if (u > T) {
            selu[pg] = u; seliA[pg] = pos; ++pg;
        } else if (u == T) {
            if (pe < kneed) { selu[totGT + pe] = u; seliA[totGT + pe] = pos; }
            ++pe;
        }
    }
    __syncthreads();

    if (t < K) {
        unsigned int u = selu[t];
        int pos = seliA[t];
        // bitonic sort 64 pairs across wave 0, descending by (u, then -pos)
        #pragma unroll
        for (int k2 = 2; k2 <= 64; k2 <<= 1) {
            #pragma unroll
            for (int j = k2 >> 1; j >= 1; j >>= 1) {
                unsigned int ou = __shfl_xor(u, j, 64);
                int opos = __shfl_xor(pos, j, 64);
                bool lower = (t & j) == 0;
                bool descB = (t & k2) == 0;
                bool otherGreater = (ou > u) || (ou == u && opos < pos);
                if (otherGreater == (lower == descB)) { u = ou; pos = opos; }
            }
        }
        unsigned int fu = (u & 0x80000000u) ? (u ^ 0x80000000u) : ~u;
        float selv = __uint_as_float(fu);

        bool m = (u != MASKED_KEY);
        float x = m ? selv : -1e9f;
        float mx = x;
        #pragma unroll
        for (int mm = 1; mm <= 32; mm <<= 1) mx = fmaxf(mx, __shfl_xor(mx, mm, 64));
        float e = expf(x - mx);
        float sm = e;
        #pragma unroll
        for (int mm = 1; mm <= 32; mm <<= 1) sm += __shfl_xor(sm, mm, 64);
        out_idx[b * K + t] = (float)pos;
        out_mask[b * K + t] = m ? 1.f : 0.f;
        out_imp[b * K + t] = e / sm;
        sortedIdx[t] = pos;
    }
    __syncthreads();

    for (int r = w; r < K; r += 4) {
        int idx = sortedIdx[r];
        float4 x = ((const float4*)(latent + ((size_t)b * N + idx) * D))[l];
        ((float4*)(out_tok + ((size_t)b * K + r) * D))[l] = x;
    }
    float gs = 0.f;
    for (int c = 0; c < CH; ++c) gs += partials[((size_t)b * CH + c) * D + t];
    out_glob[b * D + t] = gs / cnt[b];
}

extern "C" void kernel_launch(void* const* d_in, const int* in_sizes, int n_in,
                              void* d_out, int out_size, void* d_ws, size_t ws_size,
                              hipStream_t stream) {
    const float* latent = (const float*)d_in[0];
    const void*  maskp  = d_in[1];
    const float* Wq = (const float*)d_in[2];
    const float* bq = (const float*)d_in[3];
    const float* Wk = (const float*)d_in[4];
    const float* bk = (const float*)d_in[5];
    const float* Ws = (const float*)d_in[6];
    const float* bs = (const float*)d_in[7];

    float* ws = (float*)d_ws;
    float* v      = ws + OFF_V;
    float* c2     = ws + OFF_C2;
    float* cnt    = ws + OFF_CNT;
    unsigned int* keys = (unsigned int*)(ws + OFF_KEYS);
    float* part   = ws + OFF_PART;
    int*   modep  = (int*)(ws + OFF_MODE);
    int*   done   = (int*)(ws + OFF_DONE);
    float* Mhat   = ws + OFF_MHAT;
    float* u0     = ws + OFF_U0;
    float* w2     = ws + OFF_W2;
    float* cst2   = ws + OFF_CST2;
    float* out = (float*)d_out;

    hipLaunchKernelGGL(prep0_kernel, dim3(D + 1), dim3(256), 0, stream,
                       Wq, bq, Wk, bk, Ws, bs, Mhat, u0, w2, cst2, done);
    hipLaunchKernelGGL(prep1_kernel, dim3(B), dim3(256), 0, stream,
                       latent, maskp, Mhat, u0, w2, cst2, v, c2, cnt, modep);
    hipLaunchKernelGGL(main_kernel, dim3(B, CH), dim3(256), 0, stream,
                       latent, maskp, modep, v, c2, cnt, keys, part, done,
                       out + O_MASK, out + O_IDX, out + O_IMP, out + O_TOK, out + O_GLOB);
}

// Round 9
// 97.745 us; speedup vs baseline: 3.5118x; 3.5118x over previous
//
#include <hip/hip_runtime.h>
#include <math.h>

#define B 128
#define N 2048
#define D 256
#define K 64
#define CH 16          // chunks per batch in main kernel
#define RPB (N / CH)   // rows per block = 128
#define MASKED_KEY 0x007FFFFFu   // = map(-inf); strictly below every finite-score key

typedef unsigned long long u64;

// ---------------- workspace layout (in floats) ----------------
#define OFF_V       0                          // B*D
#define OFF_C2      (OFF_V + B * D)            // B
#define OFF_CNT     (OFF_C2 + B)               // B
#define OFF_KEYS    (OFF_CNT + B)              // B*N uints
#define OFF_PART    (OFF_KEYS + B * N)         // B*CH*D
#define OFF_MODE    (OFF_PART + B * CH * D)    // 64 (aligned pad)
#define OFF_MHAT    (OFF_MODE + 64)            // D*D
#define OFF_U0      (OFF_MHAT + D * D)         // D
#define OFF_W2      (OFF_U0 + D)               // D
#define OFF_CST2    (OFF_W2 + D)               // 1

// ---------------- output layout (in floats) ----------------
#define O_TOK   0                      // B*K*D
#define O_MASK  (O_TOK + B * K * D)    // B*K
#define O_IDX   (O_MASK + B * K)       // B*K
#define O_IMP   (O_IDX + B * K)        // B*K
#define O_GLOB  (O_IMP + B * K)        // B*D

__device__ __forceinline__ bool mask_at(const void* p, int mode, int i) {
    if (mode == 1) return ((const unsigned char*)p)[i] != 0;
    if (mode == 2) return ((const float*)p)[i] != 0.0f;
    return ((const int*)p)[i] != 0;
}

// Full bitonic sort, descending across 64 lanes (by u64 value).
__device__ __forceinline__ u64 wave_sort_desc(u64 P, int l) {
    #pragma unroll
    for (int k2 = 2; k2 <= 64; k2 <<= 1) {
        #pragma unroll
        for (int j = k2 >> 1; j >= 1; j >>= 1) {
            u64 o = __shfl_xor(P, j, 64);
            bool lower = (l & j) == 0;
            bool descB = (l & k2) == 0;
            bool og = o > P;
            if (og == (lower == descB)) P = o;
        }
    }
    return P;
}

// Bitonic merge, descending (input bitonic), whole wave.
__device__ __forceinline__ u64 wave_merge_desc(u64 P, int l) {
    #pragma unroll
    for (int j = 32; j >= 1; j >>= 1) {
        u64 o = __shfl_xor(P, j, 64);
        bool lower = (l & j) == 0;
        bool og = o > P;
        if (og == lower) P = o;
    }
    return P;
}

// Batch-independent fold: Mhat = (Wq^T Wk)/16, u0 = (bq^T Wk)/16 + Ws,
// w2 = (Wq^T bk)/16, cst2 = (bq.bk)/16 + bs.
__global__ __launch_bounds__(256) void prep0_kernel(
        const float* __restrict__ Wq, const float* __restrict__ bq,
        const float* __restrict__ Wk, const float* __restrict__ bk,
        const float* __restrict__ Ws, const float* __restrict__ bs,
        float* __restrict__ Mhat, float* __restrict__ u0,
        float* __restrict__ w2, float* __restrict__ cst2) {
    int e = blockIdx.x, t = threadIdx.x;
    __shared__ float col[D];
    col[t] = (e < D) ? Wq[(size_t)t * D + e] : bq[t];
    __syncthreads();
    float acc = 0.f;
    #pragma unroll 8
    for (int r = 0; r < D; ++r) acc = fmaf(col[r], Wk[(size_t)r * D + t], acc);
    if (e < D) Mhat[(size_t)e * D + t] = acc * 0.0625f;
    else       u0[t] = acc * 0.0625f + Ws[t];
    if (t < 64) {
        float p = 0.f;
        #pragma unroll
        for (int j = 0; j < 4; ++j) p = fmaf(col[t + 64 * j], bk[t + 64 * j], p);
        #pragma unroll
        for (int m = 32; m >= 1; m >>= 1) p += __shfl_xor(p, m, 64);
        if (t == 0) {
            if (e < D) w2[e] = p * 0.0625f;
            else       cst2[0] = p * 0.0625f + bs[0];
        }
    }
}

// Per-batch: mode-detect; v_b = ego_b @ Mhat + u0; c2_b = ego_b . w2 + cst2; cnt.
__global__ __launch_bounds__(256) void prep1_kernel(
        const float* __restrict__ latent, const void* __restrict__ maskp,
        const float* __restrict__ Mhat, const float* __restrict__ u0,
        const float* __restrict__ w2, const float* __restrict__ cst2,
        float* __restrict__ v, float* __restrict__ c2, float* __restrict__ cnt,
        int* __restrict__ modep) {
    int b = blockIdx.x, t = threadIdx.x, w = t >> 6, l = t & 63;
    __shared__ float ego[D];
    __shared__ int smode;
    if (w == 0) {
        const unsigned int* mw = (const unsigned int*)maskp;
        bool isF = false, hasHigh = false;
        for (int i = 0; i < 16; ++i) {
            unsigned int x = mw[l * 16 + i];
            if (x == 0x3F800000u) isF = true;
            if (x & 0xFFFFFF00u) hasHigh = true;
        }
        unsigned long long bf = __ballot(isF);
        unsigned long long bh = __ballot(hasHigh);
        if (l == 0) smode = bf ? 2 : (bh ? 1 : 0);
    }
    ego[t] = latent[(size_t)b * N * D + t];
    __syncthreads();
    int mode = smode;
    if (b == 0 && t == 0) *modep = mode;

    float acc = 0.f;
    #pragma unroll 16
    for (int e = 0; e < D; ++e) acc = fmaf(ego[e], Mhat[(size_t)e * D + t], acc);
    v[b * D + t] = acc + u0[t];

    if (t < 64) {
        float p = 0.f;
        #pragma unroll
        for (int j = 0; j < 4; ++j) p = fmaf(ego[t + 64 * j], w2[t + 64 * j], p);
        #pragma unroll
        for (int m = 32; m >= 1; m >>= 1) p += __shfl_xor(p, m, 64);
        if (t == 0) c2[b] = p + cst2[0];
    }
    int local = 0;
    for (int i = 0; i < N / D; ++i) local += mask_at(maskp, mode, b * N + t + D * i) ? 1 : 0;
    __shared__ int ctot;
    if (t == 0) ctot = 0;
    __syncthreads();
    atomicAdd(&ctot, local);
    __syncthreads();
    if (t == 0) cnt[b] = (float)ctot;
}

// Streaming pass: 16 lanes per row, 4 rows per wave-iteration.
// Writes order-preserving uint keys (masked -> MASKED_KEY) + partial column sums.
__global__ __launch_bounds__(256) void main_kernel(
        const float* __restrict__ latent, const void* __restrict__ maskp,
        const int* __restrict__ modep,
        const float* __restrict__ v, const float* __restrict__ c2,
        unsigned int* __restrict__ keys, float* __restrict__ partials) {
    int b = blockIdx.y, ch = blockIdx.x;
    int t = threadIdx.x, w = t >> 6, l = t & 63;
    int g = l >> 4, i = l & 15;
    int mode = *modep;
    const float4* v4 = (const float4*)(v + b * D);
    float4 vv0 = v4[i], vv1 = v4[i + 16], vv2 = v4[i + 32], vv3 = v4[i + 48];
    float c2b = c2[b];
    float4 a0 = {0,0,0,0}, a1 = {0,0,0,0}, a2 = {0,0,0,0}, a3 = {0,0,0,0};
    const float4* lat4 = (const float4*)(latent + (size_t)b * N * D);
    int n0 = ch * RPB + w * (RPB / 4);   // 32 rows per wave
    for (int it = 0; it < RPB / 16; ++it) {
        int n = n0 + it * 4 + g;
        const float4* row = lat4 + (size_t)n * (D / 4);
        float4 x0 = row[i], x1 = row[i + 16], x2 = row[i + 32], x3 = row[i + 48];
        float p = x0.x * vv0.x;
        p = fmaf(x0.y, vv0.y, p); p = fmaf(x0.z, vv0.z, p); p = fmaf(x0.w, vv0.w, p);
        p = fmaf(x1.x, vv1.x, p); p = fmaf(x1.y, vv1.y, p);
        p = fmaf(x1.z, vv1.z, p); p = fmaf(x1.w, vv1.w, p);
        p = fmaf(x2.x, vv2.x, p); p = fmaf(x2.y, vv2.y, p);
        p = fmaf(x2.z, vv2.z, p); p = fmaf(x2.w, vv2.w, p);
        p = fmaf(x3.x, vv3.x, p); p = fmaf(x3.y, vv3.y, p);
        p = fmaf(x3.z, vv3.z, p); p = fmaf(x3.w, vv3.w, p);
        #pragma unroll
        for (int m = 8; m >= 1; m >>= 1) p += __shfl_xor(p, m, 64);  // 16-lane reduce
        bool msk = mask_at(maskp, mode, b * N + n);
        if (i == 0) {
            unsigned int ky = MASKED_KEY;
            if (msk) {
                unsigned int fu = __float_as_uint(p + c2b);
                ky = (fu & 0x80000000u) ? ~fu : (fu | 0x80000000u);
            }
            keys[(size_t)b * N + n] = ky;
        }
        if (msk) {
            a0.x += x0.x; a0.y += x0.y; a0.z += x0.z; a0.w += x0.w;
            a1.x += x1.x; a1.y += x1.y; a1.z += x1.z; a1.w += x1.w;
            a2.x += x2.x; a2.y += x2.y; a2.z += x2.z; a2.w += x2.w;
            a3.x += x3.x; a3.y += x3.y; a3.z += x3.z; a3.w += x3.w;
        }
    }
    __shared__ float red[16][D];
    float4* rr = (float4*)red[w * 4 + g];
    rr[i] = a0; rr[i + 16] = a1; rr[i + 32] = a2; rr[i + 48] = a3;
    __syncthreads();
    float s = 0.f;
    #pragma unroll
    for (int r = 0; r < 16; ++r) s += red[r][t];
    partials[((size_t)b * CH + ch) * D + t] = s;
}

// Fused epilogue per batch: wave-register bitonic top-64 (exact jax tie
// semantics via (key, ~pos) packing) -> mask/softmax/index -> gather ->
// global_latent. No radix, no LDS atomics, 3 __syncthreads total.
__global__ __launch_bounds__(256) void epilogue_kernel(
        const unsigned int* __restrict__ keysg, const float* __restrict__ latent,
        const float* __restrict__ partials, const float* __restrict__ cnt,
        float* __restrict__ out_mask, float* __restrict__ out_idx,
        float* __restrict__ out_imp, float* __restrict__ out_tok,
        float* __restrict__ out_glob) {
    int b = blockIdx.x, t = threadIdx.x, w = t >> 6, l = t & 63;
    __shared__ u64 lists[4][K];
    __shared__ int sortedIdx[K];

    const unsigned int* kb = keysg + (size_t)b * N;
    // wave w owns keys [w*512, (w+1)*512): 8 chunks of 64
    u64 cur = 0;
    #pragma unroll
    for (int c = 0; c < 8; ++c) {
        int pos = w * 512 + c * 64 + l;
        unsigned int u = kb[pos];
        u64 P = ((u64)u << 16) | (u64)(2047 - pos);   // desc value, asc index
        P = wave_sort_desc(P, l);
        if (c == 0) {
            cur = P;
        } else {
            u64 rev = __shfl_xor(P, 63, 64);          // reverse sorted chunk
            cur = (cur > rev) ? cur : rev;            // bitonic top-64
            cur = wave_merge_desc(cur, l);
        }
    }
    lists[w][l] = cur;
    __syncthreads();

    if (w == 0) {
        #pragma unroll
        for (int w2 = 1; w2 < 4; ++w2) {
            u64 rev = lists[w2][63 - l];
            cur = (cur > rev) ? cur : rev;
            cur = wave_merge_desc(cur, l);
        }
        // cur is the final sorted top-64 (desc by value, asc by index)
        unsigned int u = (unsigned int)(cur >> 16);
        int pos = 2047 - (int)(cur & 0xFFFFu);
        unsigned int fu = (u & 0x80000000u) ? (u ^ 0x80000000u) : ~u;
        float selv = __uint_as_float(fu);
        bool m = (u != MASKED_KEY);
        float x = m ? selv : -1e9f;
        float mx = x;
        #pragma unroll
        for (int mm = 1; mm <= 32; mm <<= 1) mx = fmaxf(mx, __shfl_xor(mx, mm, 64));
        float e = expf(x - mx);
        float sm = e;
        #pragma unroll
        for (int mm = 1; mm <= 32; mm <<= 1) sm += __shfl_xor(sm, mm, 64);
        out_idx[b * K + l] = (float)pos;
        out_mask[b * K + l] = m ? 1.f : 0.f;
        out_imp[b * K + l] = e / sm;
        sortedIdx[l] = pos;
    }
    __syncthreads();

    // gather selected tokens (sorted order), 4 waves x 16 rows, float4 rows
    for (int r = w; r < K; r += 4) {
        int idx = sortedIdx[r];
        float4 x = ((const float4*)(latent + ((size_t)b * N + idx) * D))[l];
        ((float4*)(out_tok + ((size_t)b * K + r) * D))[l] = x;
    }
    // global_latent finalize
    float gs = 0.f;
    #pragma unroll
    for (int c = 0; c < CH; ++c) gs += partials[((size_t)b * CH + c) * D + t];
    out_glob[b * D + t] = gs / cnt[b];
}

extern "C" void kernel_launch(void* const* d_in, const int* in_sizes, int n_in,
                              void* d_out, int out_size, void* d_ws, size_t ws_size,
                              hipStream_t stream) {
    const float* latent = (const float*)d_in[0];
    const void*  maskp  = d_in[1];
    const float* Wq = (const float*)d_in[2];
    const float* bq = (const float*)d_in[3];
    const float* Wk = (const float*)d_in[4];
    const float* bk = (const float*)d_in[5];
    const float* Ws = (const float*)d_in[6];
    const float* bs = (const float*)d_in[7];

    float* ws = (float*)d_ws;
    float* v      = ws + OFF_V;
    float* c2     = ws + OFF_C2;
    float* cnt    = ws + OFF_CNT;
    unsigned int* keys = (unsigned int*)(ws + OFF_KEYS);
    float* part   = ws + OFF_PART;
    int*   modep  = (int*)(ws + OFF_MODE);
    float* Mhat   = ws + OFF_MHAT;
    float* u0     = ws + OFF_U0;
    float* w2     = ws + OFF_W2;
    float* cst2   = ws + OFF_CST2;
    float* out = (float*)d_out;

    hipLaunchKernelGGL(prep0_kernel, dim3(D + 1), dim3(256), 0, stream,
                       Wq, bq, Wk, bk, Ws, bs, Mhat, u0, w2, cst2);
    hipLaunchKernelGGL(prep1_kernel, dim3(B), dim3(256), 0, stream,
                       latent, maskp, Mhat, u0, w2, cst2, v, c2, cnt, modep);
    hipLaunchKernelGGL(main_kernel, dim3(CH, B), dim3(256), 0, stream,
                       latent, maskp, modep, v, c2, keys, part);
    hipLaunchKernelGGL(epilogue_kernel, dim3(B), dim3(256), 0, stream,
                       keys, latent, part, cnt,
                       out + O_MASK, out + O_IDX, out + O_IMP, out + O_TOK, out + O_GLOB);
}

// Round 10
// 81.696 us; speedup vs baseline: 4.2016x; 1.1964x over previous
//
#include <hip/hip_runtime.h>
#include <math.h>

#define B 128
#define N 2048
#define D 256
#define K 64
#define CH 16          // chunks per batch in main kernel
#define MASKED_KEY 0x007FFFFFu   // = map(-inf); strictly below every finite-score key

typedef unsigned long long u64;
typedef float nfloat4 __attribute__((ext_vector_type(4)));   // native vec for nontemporal builtin

// ---------------- workspace layout (in floats) ----------------
#define OFF_V       0                          // B*D
#define OFF_C2      (OFF_V + B * D)            // B
#define OFF_CNT     (OFF_C2 + B)               // B
#define OFF_KEYS    (OFF_CNT + B)              // B*N uints
#define OFF_PART    (OFF_KEYS + B * N)         // B*CH*D
#define OFF_MODE    (OFF_PART + B * CH * D)    // 64 (aligned pad)
#define OFF_MHAT    (OFF_MODE + 64)            // D*D
#define OFF_U0      (OFF_MHAT + D * D)         // D
#define OFF_W2      (OFF_U0 + D)               // D
#define OFF_CST2    (OFF_W2 + D)               // 64 (pad)
#define OFF_ROWS    (OFF_CST2 + 64)            // B*N ints (compacted masked rows)

// ---------------- output layout (in floats) ----------------
#define O_TOK   0                      // B*K*D
#define O_MASK  (O_TOK + B * K * D)    // B*K
#define O_IDX   (O_MASK + B * K)       // B*K
#define O_IMP   (O_IDX + B * K)        // B*K
#define O_GLOB  (O_IMP + B * K)        // B*D

__device__ __forceinline__ bool mask_at(const void* p, int mode, int i) {
    if (mode == 1) return ((const unsigned char*)p)[i] != 0;
    if (mode == 2) return ((const float*)p)[i] != 0.0f;
    return ((const int*)p)[i] != 0;
}

// in-wave inclusive scan (64 lanes)
__device__ __forceinline__ int wave_iscan(int x, int l) {
    #pragma unroll
    for (int d = 1; d < 64; d <<= 1) {
        int y = __shfl_up(x, d, 64);
        if (l >= d) x += y;
    }
    return x;
}

// Full bitonic sort, descending across 64 lanes (by u64 value).
__device__ __forceinline__ u64 wave_sort_desc(u64 P, int l) {
    #pragma unroll
    for (int k2 = 2; k2 <= 64; k2 <<= 1) {
        #pragma unroll
        for (int j = k2 >> 1; j >= 1; j >>= 1) {
            u64 o = __shfl_xor(P, j, 64);
            bool lower = (l & j) == 0;
            bool descB = (l & k2) == 0;
            bool og = o > P;
            if (og == (lower == descB)) P = o;
        }
    }
    return P;
}

// Bitonic merge, descending (input bitonic), whole wave.
__device__ __forceinline__ u64 wave_merge_desc(u64 P, int l) {
    #pragma unroll
    for (int j = 32; j >= 1; j >>= 1) {
        u64 o = __shfl_xor(P, j, 64);
        bool lower = (l & j) == 0;
        bool og = o > P;
        if (og == lower) P = o;
    }
    return P;
}

// Batch-independent fold: Mhat = (Wq^T Wk)/16, u0 = (bq^T Wk)/16 + Ws,
// w2 = (Wq^T bk)/16, cst2 = (bq.bk)/16 + bs.
__global__ __launch_bounds__(256) void prep0_kernel(
        const float* __restrict__ Wq, const float* __restrict__ bq,
        const float* __restrict__ Wk, const float* __restrict__ bk,
        const float* __restrict__ Ws, const float* __restrict__ bs,
        float* __restrict__ Mhat, float* __restrict__ u0,
        float* __restrict__ w2, float* __restrict__ cst2) {
    int e = blockIdx.x, t = threadIdx.x;
    __shared__ float col[D];
    col[t] = (e < D) ? Wq[(size_t)t * D + e] : bq[t];
    __syncthreads();
    float acc = 0.f;
    #pragma unroll 8
    for (int r = 0; r < D; ++r) acc = fmaf(col[r], Wk[(size_t)r * D + t], acc);
    if (e < D) Mhat[(size_t)e * D + t] = acc * 0.0625f;
    else       u0[t] = acc * 0.0625f + Ws[t];
    if (t < 64) {
        float p = 0.f;
        #pragma unroll
        for (int j = 0; j < 4; ++j) p = fmaf(col[t + 64 * j], bk[t + 64 * j], p);
        #pragma unroll
        for (int m = 32; m >= 1; m >>= 1) p += __shfl_xor(p, m, 64);
        if (t == 0) {
            if (e < D) w2[e] = p * 0.0625f;
            else       cst2[0] = p * 0.0625f + bs[0];
        }
    }
}

// Per-batch: mode-detect; v_b = ego_b @ Mhat + u0; c2_b = ego_b . w2 + cst2;
// compacted masked-row list (ascending) + MASKED_KEY prefill for unmasked; cnt.
__global__ __launch_bounds__(256) void prep1_kernel(
        const float* __restrict__ latent, const void* __restrict__ maskp,
        const float* __restrict__ Mhat, const float* __restrict__ u0,
        const float* __restrict__ w2, const float* __restrict__ cst2,
        float* __restrict__ v, float* __restrict__ c2, float* __restrict__ cnt,
        int* __restrict__ modep, int* __restrict__ rowlist,
        unsigned int* __restrict__ keys) {
    int b = blockIdx.x, t = threadIdx.x, w = t >> 6, l = t & 63;
    __shared__ float ego[D];
    __shared__ int smode;
    __shared__ int wtot[4];
    if (w == 0) {
        const unsigned int* mw = (const unsigned int*)maskp;
        bool isF = false, hasHigh = false;
        for (int i = 0; i < 16; ++i) {
            unsigned int x = mw[l * 16 + i];
            if (x == 0x3F800000u) isF = true;
            if (x & 0xFFFFFF00u) hasHigh = true;
        }
        unsigned long long bf = __ballot(isF);
        unsigned long long bh = __ballot(hasHigh);
        if (l == 0) smode = bf ? 2 : (bh ? 1 : 0);
    }
    ego[t] = latent[(size_t)b * N * D + t];
    __syncthreads();
    int mode = smode;
    if (b == 0 && t == 0) *modep = mode;

    float acc = 0.f;
    #pragma unroll 16
    for (int e = 0; e < D; ++e) acc = fmaf(ego[e], Mhat[(size_t)e * D + t], acc);
    v[b * D + t] = acc + u0[t];

    if (t < 64) {
        float p = 0.f;
        #pragma unroll
        for (int j = 0; j < 4; ++j) p = fmaf(ego[t + 64 * j], w2[t + 64 * j], p);
        #pragma unroll
        for (int m = 32; m >= 1; m >>= 1) p += __shfl_xor(p, m, 64);
        if (t == 0) c2[b] = p + cst2[0];
    }

    // ---- compaction: thread t owns positions [t*8, t*8+8) (order-preserving) ----
    bool mloc[8];
    int c = 0;
    #pragma unroll
    for (int j = 0; j < 8; ++j) {
        mloc[j] = mask_at(maskp, mode, b * N + t * 8 + j);
        c += mloc[j] ? 1 : 0;
    }
    int incl = wave_iscan(c, l);
    if (l == 63) wtot[w] = incl;
    __syncthreads();
    int off = incl - c;
    #pragma unroll
    for (int ww = 0; ww < 4; ++ww) if (ww < w) off += wtot[ww];
    int ctot = wtot[0] + wtot[1] + wtot[2] + wtot[3];
    #pragma unroll
    for (int j = 0; j < 8; ++j) {
        int pos = t * 8 + j;
        if (mloc[j]) rowlist[(size_t)b * N + (off++)] = pos;
        else keys[(size_t)b * N + pos] = MASKED_KEY;
    }
    if (t == 0) cnt[b] = (float)ctot;
}

// Streaming pass over MASKED rows only (compacted list). 16 lanes per row,
// 4 rows per wave-iteration, nontemporal latent loads. Writes keys + partials.
__global__ __launch_bounds__(256) void main_kernel(
        const float* __restrict__ latent,
        const float* __restrict__ cnt, const int* __restrict__ rowlist,
        const float* __restrict__ v, const float* __restrict__ c2,
        unsigned int* __restrict__ keys, float* __restrict__ partials) {
    int b = blockIdx.y, ch = blockIdx.x;
    int t = threadIdx.x, w = t >> 6, l = t & 63;
    int g = l >> 4, i = l & 15;
    const float4* v4 = (const float4*)(v + b * D);
    float4 vv0 = v4[i], vv1 = v4[i + 16], vv2 = v4[i + 32], vv3 = v4[i + 48];
    float c2b = c2[b];
    float ax0=0,ay0=0,az0=0,aw0=0, ax1=0,ay1=0,az1=0,aw1=0;
    float ax2=0,ay2=0,az2=0,aw2=0, ax3=0,ay3=0,az3=0,aw3=0;
    const nfloat4* lat4 = (const nfloat4*)(latent + (size_t)b * N * D);
    const int* rl = rowlist + (size_t)b * N;
    int cntb = (int)cnt[b];
    int j0 = (ch * cntb) / CH, j1 = ((ch + 1) * cntb) / CH;
    for (int j = j0 + w * 4 + g; j < j1; j += 16) {
        int n = rl[j];
        const nfloat4* row = lat4 + (size_t)n * (D / 4);
        nfloat4 x0 = __builtin_nontemporal_load(&row[i]);
        nfloat4 x1 = __builtin_nontemporal_load(&row[i + 16]);
        nfloat4 x2 = __builtin_nontemporal_load(&row[i + 32]);
        nfloat4 x3 = __builtin_nontemporal_load(&row[i + 48]);
        float p = x0.x * vv0.x;
        p = fmaf(x0.y, vv0.y, p); p = fmaf(x0.z, vv0.z, p); p = fmaf(x0.w, vv0.w, p);
        p = fmaf(x1.x, vv1.x, p); p = fmaf(x1.y, vv1.y, p);
        p = fmaf(x1.z, vv1.z, p); p = fmaf(x1.w, vv1.w, p);
        p = fmaf(x2.x, vv2.x, p); p = fmaf(x2.y, vv2.y, p);
        p = fmaf(x2.z, vv2.z, p); p = fmaf(x2.w, vv2.w, p);
        p = fmaf(x3.x, vv3.x, p); p = fmaf(x3.y, vv3.y, p);
        p = fmaf(x3.z, vv3.z, p); p = fmaf(x3.w, vv3.w, p);
        #pragma unroll
        for (int m = 8; m >= 1; m >>= 1) p += __shfl_xor(p, m, 64);  // 16-lane reduce
        if (i == 0) {
            unsigned int fu = __float_as_uint(p + c2b);
            keys[(size_t)b * N + n] = (fu & 0x80000000u) ? ~fu : (fu | 0x80000000u);
        }
        ax0 += x0.x; ay0 += x0.y; az0 += x0.z; aw0 += x0.w;
        ax1 += x1.x; ay1 += x1.y; az1 += x1.z; aw1 += x1.w;
        ax2 += x2.x; ay2 += x2.y; az2 += x2.z; aw2 += x2.w;
        ax3 += x3.x; ay3 += x3.y; az3 += x3.z; aw3 += x3.w;
    }
    __shared__ float red[16][D];
    float* rr = red[w * 4 + g];
    rr[i*4+0]=ax0; rr[i*4+1]=ay0; rr[i*4+2]=az0; rr[i*4+3]=aw0;
    rr[64+i*4+0]=ax1; rr[64+i*4+1]=ay1; rr[64+i*4+2]=az1; rr[64+i*4+3]=aw1;
    rr[128+i*4+0]=ax2; rr[128+i*4+1]=ay2; rr[128+i*4+2]=az2; rr[128+i*4+3]=aw2;
    rr[192+i*4+0]=ax3; rr[192+i*4+1]=ay3; rr[192+i*4+2]=az3; rr[192+i*4+3]=aw3;
    __syncthreads();
    float s = 0.f;
    #pragma unroll
    for (int r = 0; r < 16; ++r) s += red[r][t];
    partials[((size_t)b * CH + ch) * D + t] = s;
}

// Fused epilogue per batch: wave-register bitonic top-64 (exact jax tie
// semantics via (key, ~pos) packing) -> mask/softmax/index -> gather ->
// global_latent.
__global__ __launch_bounds__(256) void epilogue_kernel(
        const unsigned int* __restrict__ keysg, const float* __restrict__ latent,
        const float* __restrict__ partials, const float* __restrict__ cnt,
        float* __restrict__ out_mask, float* __restrict__ out_idx,
        float* __restrict__ out_imp, float* __restrict__ out_tok,
        float* __restrict__ out_glob) {
    int b = blockIdx.x, t = threadIdx.x, w = t >> 6, l = t & 63;
    __shared__ u64 lists[4][K];
    __shared__ int sortedIdx[K];

    const unsigned int* kb = keysg + (size_t)b * N;
    u64 cur = 0;
    #pragma unroll
    for (int c = 0; c < 8; ++c) {
        int pos = w * 512 + c * 64 + l;
        unsigned int u = kb[pos];
        u64 P = ((u64)u << 16) | (u64)(2047 - pos);   // desc value, asc index
        P = wave_sort_desc(P, l);
        if (c == 0) {
            cur = P;
        } else {
            u64 rev = __shfl_xor(P, 63, 64);
            cur = (cur > rev) ? cur : rev;
            cur = wave_merge_desc(cur, l);
        }
    }
    lists[w][l] = cur;
    __syncthreads();

    if (w == 0) {
        #pragma unroll
        for (int w2 = 1; w2 < 4; ++w2) {
            u64 rev = lists[w2][63 - l];
            cur = (cur > rev) ? cur : rev;
            cur = wave_merge_desc(cur, l);
        }
        unsigned int u = (unsigned int)(cur >> 16);
        int pos = 2047 - (int)(cur & 0xFFFFu);
        unsigned int fu = (u & 0x80000000u) ? (u ^ 0x80000000u) : ~u;
        float selv = __uint_as_float(fu);
        bool m = (u != MASKED_KEY);
        float x = m ? selv : -1e9f;
        float mx = x;
        #pragma unroll
        for (int mm = 1; mm <= 32; mm <<= 1) mx = fmaxf(mx, __shfl_xor(mx, mm, 64));
        float e = expf(x - mx);
        float sm = e;
        #pragma unroll
        for (int mm = 1; mm <= 32; mm <<= 1) sm += __shfl_xor(sm, mm, 64);
        out_idx[b * K + l] = (float)pos;
        out_mask[b * K + l] = m ? 1.f : 0.f;
        out_imp[b * K + l] = e / sm;
        sortedIdx[l] = pos;
    }
    __syncthreads();

    for (int r = w; r < K; r += 4) {
        int idx = sortedIdx[r];
        float4 x = ((const float4*)(latent + ((size_t)b * N + idx) * D))[l];
        ((float4*)(out_tok + ((size_t)b * K + r) * D))[l] = x;
    }
    float gs = 0.f;
    #pragma unroll
    for (int c = 0; c < CH; ++c) gs += partials[((size_t)b * CH + c) * D + t];
    out_glob[b * D + t] = gs / cnt[b];
}

extern "C" void kernel_launch(void* const* d_in, const int* in_sizes, int n_in,
                              void* d_out, int out_size, void* d_ws, size_t ws_size,
                              hipStream_t stream) {
    const float* latent = (const float*)d_in[0];
    const void*  maskp  = d_in[1];
    const float* Wq = (const float*)d_in[2];
    const float* bq = (const float*)d_in[3];
    const float* Wk = (const float*)d_in[4];
    const float* bk = (const float*)d_in[5];
    const float* Ws = (const float*)d_in[6];
    const float* bs = (const float*)d_in[7];

    float* ws = (float*)d_ws;
    float* v      = ws + OFF_V;
    float* c2     = ws + OFF_C2;
    float* cnt    = ws + OFF_CNT;
    unsigned int* keys = (unsigned int*)(ws + OFF_KEYS);
    float* part   = ws + OFF_PART;
    int*   modep  = (int*)(ws + OFF_MODE);
    float* Mhat   = ws + OFF_MHAT;
    float* u0     = ws + OFF_U0;
    float* w2     = ws + OFF_W2;
    float* cst2   = ws + OFF_CST2;
    int*   rowlist = (int*)(ws + OFF_ROWS);
    float* out = (float*)d_out;

    hipLaunchKernelGGL(prep0_kernel, dim3(D + 1), dim3(256), 0, stream,
                       Wq, bq, Wk, bk, Ws, bs, Mhat, u0, w2, cst2);
    hipLaunchKernelGGL(prep1_kernel, dim3(B), dim3(256), 0, stream,
                       latent, maskp, Mhat, u0, w2, cst2, v, c2, cnt, modep, rowlist, keys);
    hipLaunchKernelGGL(main_kernel, dim3(CH, B), dim3(256), 0, stream,
                       latent, cnt, rowlist, v, c2, keys, part);
    hipLaunchKernelGGL(epilogue_kernel, dim3(B), dim3(256), 0, stream,
                       keys, latent, part, cnt,
                       out + O_MASK, out + O_IDX, out + O_IMP, out + O_TOK, out + O_GLOB);
}

// Round 11
// 77.390 us; speedup vs baseline: 4.4354x; 1.0556x over previous
//
#include <hip/hip_runtime.h>
#include <math.h>

#define B 128
#define N 2048
#define D 256
#define K 64
#define CH 16          // chunks per batch in main kernel
#define MASKED_KEY 0x007FFFFFu   // = map(-inf); strictly below every finite-score key

typedef unsigned long long u64;
typedef float nfloat4 __attribute__((ext_vector_type(4)));   // native vec for nontemporal builtin

// ---------------- workspace layout (in floats) ----------------
#define OFF_V       0                          // B*D
#define OFF_C2      (OFF_V + B * D)            // B
#define OFF_CNT     (OFF_C2 + B)               // B
#define OFF_PART    (OFF_CNT + B)              // B*CH*D
#define OFF_MODE    (OFF_PART + B * CH * D)    // 64 (aligned pad)
#define OFF_MHAT    (OFF_MODE + 64)            // D*D
#define OFF_U0      (OFF_MHAT + D * D)         // D
#define OFF_W2      (OFF_U0 + D)               // D
#define OFF_CST2    (OFF_W2 + D)               // 64 (pad)
#define OFF_ROWS    (OFF_CST2 + 64)            // B*N ints (compacted masked rows)
#define OFF_LISTS   (OFF_ROWS + B * N)         // B*CH*K u64 = B*CH*K*2 floats (8B-aligned)

// ---------------- output layout (in floats) ----------------
#define O_TOK   0                      // B*K*D
#define O_MASK  (O_TOK + B * K * D)    // B*K
#define O_IDX   (O_MASK + B * K)       // B*K
#define O_IMP   (O_IDX + B * K)        // B*K
#define O_GLOB  (O_IMP + B * K)        // B*D

__device__ __forceinline__ bool mask_at(const void* p, int mode, int i) {
    if (mode == 1) return ((const unsigned char*)p)[i] != 0;
    if (mode == 2) return ((const float*)p)[i] != 0.0f;
    return ((const int*)p)[i] != 0;
}

// in-wave inclusive scan (64 lanes)
__device__ __forceinline__ int wave_iscan(int x, int l) {
    #pragma unroll
    for (int d = 1; d < 64; d <<= 1) {
        int y = __shfl_up(x, d, 64);
        if (l >= d) x += y;
    }
    return x;
}

// Full bitonic sort, descending across 64 lanes (by u64 value).
__device__ __forceinline__ u64 wave_sort_desc(u64 P, int l) {
    #pragma unroll
    for (int k2 = 2; k2 <= 64; k2 <<= 1) {
        #pragma unroll
        for (int j = k2 >> 1; j >= 1; j >>= 1) {
            u64 o = __shfl_xor(P, j, 64);
            bool lower = (l & j) == 0;
            bool descB = (l & k2) == 0;
            bool og = o > P;
            if (og == (lower == descB)) P = o;
        }
    }
    return P;
}

// Bitonic merge, descending (input bitonic), whole wave.
__device__ __forceinline__ u64 wave_merge_desc(u64 P, int l) {
    #pragma unroll
    for (int j = 32; j >= 1; j >>= 1) {
        u64 o = __shfl_xor(P, j, 64);
        bool lower = (l & j) == 0;
        bool og = o > P;
        if (og == lower) P = o;
    }
    return P;
}

// Batch-independent fold: Mhat = (Wq^T Wk)/16, u0 = (bq^T Wk)/16 + Ws,
// w2 = (Wq^T bk)/16, cst2 = (bq.bk)/16 + bs.
__global__ __launch_bounds__(256) void prep0_kernel(
        const float* __restrict__ Wq, const float* __restrict__ bq,
        const float* __restrict__ Wk, const float* __restrict__ bk,
        const float* __restrict__ Ws, const float* __restrict__ bs,
        float* __restrict__ Mhat, float* __restrict__ u0,
        float* __restrict__ w2, float* __restrict__ cst2) {
    int e = blockIdx.x, t = threadIdx.x;
    __shared__ float col[D];
    col[t] = (e < D) ? Wq[(size_t)t * D + e] : bq[t];
    __syncthreads();
    float acc = 0.f;
    #pragma unroll 8
    for (int r = 0; r < D; ++r) acc = fmaf(col[r], Wk[(size_t)r * D + t], acc);
    if (e < D) Mhat[(size_t)e * D + t] = acc * 0.0625f;
    else       u0[t] = acc * 0.0625f + Ws[t];
    if (t < 64) {
        float p = 0.f;
        #pragma unroll
        for (int j = 0; j < 4; ++j) p = fmaf(col[t + 64 * j], bk[t + 64 * j], p);
        #pragma unroll
        for (int m = 32; m >= 1; m >>= 1) p += __shfl_xor(p, m, 64);
        if (t == 0) {
            if (e < D) w2[e] = p * 0.0625f;
            else       cst2[0] = p * 0.0625f + bs[0];
        }
    }
}

// Per-batch: mode-detect; v_b = ego_b @ Mhat + u0; c2_b = ego_b . w2 + cst2;
// compacted masked-row list (ascending); cnt.
__global__ __launch_bounds__(256) void prep1_kernel(
        const float* __restrict__ latent, const void* __restrict__ maskp,
        const float* __restrict__ Mhat, const float* __restrict__ u0,
        const float* __restrict__ w2, const float* __restrict__ cst2,
        float* __restrict__ v, float* __restrict__ c2, float* __restrict__ cnt,
        int* __restrict__ modep, int* __restrict__ rowlist) {
    int b = blockIdx.x, t = threadIdx.x, w = t >> 6, l = t & 63;
    __shared__ float ego[D];
    __shared__ int smode;
    __shared__ int wtot[4];
    if (w == 0) {
        const unsigned int* mw = (const unsigned int*)maskp;
        bool isF = false, hasHigh = false;
        for (int i = 0; i < 16; ++i) {
            unsigned int x = mw[l * 16 + i];
            if (x == 0x3F800000u) isF = true;
            if (x & 0xFFFFFF00u) hasHigh = true;
        }
        unsigned long long bf = __ballot(isF);
        unsigned long long bh = __ballot(hasHigh);
        if (l == 0) smode = bf ? 2 : (bh ? 1 : 0);
    }
    ego[t] = latent[(size_t)b * N * D + t];
    __syncthreads();
    int mode = smode;
    if (b == 0 && t == 0) *modep = mode;

    float acc = 0.f;
    #pragma unroll 16
    for (int e = 0; e < D; ++e) acc = fmaf(ego[e], Mhat[(size_t)e * D + t], acc);
    v[b * D + t] = acc + u0[t];

    if (t < 64) {
        float p = 0.f;
        #pragma unroll
        for (int j = 0; j < 4; ++j) p = fmaf(ego[t + 64 * j], w2[t + 64 * j], p);
        #pragma unroll
        for (int m = 32; m >= 1; m >>= 1) p += __shfl_xor(p, m, 64);
        if (t == 0) c2[b] = p + cst2[0];
    }

    // ---- compaction: thread t owns positions [t*8, t*8+8) (order-preserving) ----
    bool mloc[8];
    int c = 0;
    #pragma unroll
    for (int j = 0; j < 8; ++j) {
        mloc[j] = mask_at(maskp, mode, b * N + t * 8 + j);
        c += mloc[j] ? 1 : 0;
    }
    int incl = wave_iscan(c, l);
    if (l == 63) wtot[w] = incl;
    __syncthreads();
    int off = incl - c;
    #pragma unroll
    for (int ww = 0; ww < 4; ++ww) if (ww < w) off += wtot[ww];
    int ctot = wtot[0] + wtot[1] + wtot[2] + wtot[3];
    #pragma unroll
    for (int j = 0; j < 8; ++j) {
        int pos = t * 8 + j;
        if (mloc[j]) rowlist[(size_t)b * N + (off++)] = pos;
    }
    if (t == 0) cnt[b] = (float)ctot;
}

// Streaming pass over masked rows only (compacted, LDS-prefetched slice).
// 16 lanes/row, nontemporal loads. Produces partial colsums + a SORTED
// per-chunk top-64 list (u64 = key<<16 | (2047-pos), exact jax tie order).
__global__ __launch_bounds__(256) void main_kernel(
        const float* __restrict__ latent,
        const float* __restrict__ cnt, const int* __restrict__ rowlist,
        const float* __restrict__ v, const float* __restrict__ c2,
        float* __restrict__ partials, u64* __restrict__ lists) {
    int b = blockIdx.y, ch = blockIdx.x;
    int t = threadIdx.x, w = t >> 6, l = t & 63;
    int g = l >> 4, i = l & 15;
    __shared__ float red[16][D];     // 16 KB
    __shared__ u64 cand[128];        // 1 KB
    __shared__ int rlds[128];        // 512 B

    int cntb = (int)cnt[b];
    int j0 = (ch * cntb) / CH, j1 = ((ch + 1) * cntb) / CH;
    int M = j1 - j0;                 // <= 128
    if (t < 128) cand[t] = ((u64)MASKED_KEY << 16);   // pad: below all finite keys
    if (t < M) rlds[t] = rowlist[(size_t)b * N + j0 + t];
    const float4* v4 = (const float4*)(v + b * D);
    float4 vv0 = v4[i], vv1 = v4[i + 16], vv2 = v4[i + 32], vv3 = v4[i + 48];
    float c2b = c2[b];
    float ax0=0,ay0=0,az0=0,aw0=0, ax1=0,ay1=0,az1=0,aw1=0;
    float ax2=0,ay2=0,az2=0,aw2=0, ax3=0,ay3=0,az3=0,aw3=0;
    const nfloat4* lat4 = (const nfloat4*)(latent + (size_t)b * N * D);
    __syncthreads();

    #pragma unroll 2
    for (int jj = w * 4 + g; jj < M; jj += 16) {
        int n = rlds[jj];
        const nfloat4* row = lat4 + (size_t)n * (D / 4);
        nfloat4 x0 = __builtin_nontemporal_load(&row[i]);
        nfloat4 x1 = __builtin_nontemporal_load(&row[i + 16]);
        nfloat4 x2 = __builtin_nontemporal_load(&row[i + 32]);
        nfloat4 x3 = __builtin_nontemporal_load(&row[i + 48]);
        float p = x0.x * vv0.x;
        p = fmaf(x0.y, vv0.y, p); p = fmaf(x0.z, vv0.z, p); p = fmaf(x0.w, vv0.w, p);
        p = fmaf(x1.x, vv1.x, p); p = fmaf(x1.y, vv1.y, p);
        p = fmaf(x1.z, vv1.z, p); p = fmaf(x1.w, vv1.w, p);
        p = fmaf(x2.x, vv2.x, p); p = fmaf(x2.y, vv2.y, p);
        p = fmaf(x2.z, vv2.z, p); p = fmaf(x2.w, vv2.w, p);
        p = fmaf(x3.x, vv3.x, p); p = fmaf(x3.y, vv3.y, p);
        p = fmaf(x3.z, vv3.z, p); p = fmaf(x3.w, vv3.w, p);
        #pragma unroll
        for (int m = 8; m >= 1; m >>= 1) p += __shfl_xor(p, m, 64);  // 16-lane reduce
        if (i == 0) {
            unsigned int fu = __float_as_uint(p + c2b);
            unsigned int ky = (fu & 0x80000000u) ? ~fu : (fu | 0x80000000u);
            cand[jj] = ((u64)ky << 16) | (u64)(2047 - n);
        }
        ax0 += x0.x; ay0 += x0.y; az0 += x0.z; aw0 += x0.w;
        ax1 += x1.x; ay1 += x1.y; az1 += x1.z; aw1 += x1.w;
        ax2 += x2.x; ay2 += x2.y; az2 += x2.z; aw2 += x2.w;
        ax3 += x3.x; ay3 += x3.y; az3 += x3.z; aw3 += x3.w;
    }
    float* rr = red[w * 4 + g];
    rr[i*4+0]=ax0; rr[i*4+1]=ay0; rr[i*4+2]=az0; rr[i*4+3]=aw0;
    rr[64+i*4+0]=ax1; rr[64+i*4+1]=ay1; rr[64+i*4+2]=az1; rr[64+i*4+3]=aw1;
    rr[128+i*4+0]=ax2; rr[128+i*4+1]=ay2; rr[128+i*4+2]=az2; rr[128+i*4+3]=aw2;
    rr[192+i*4+0]=ax3; rr[192+i*4+1]=ay3; rr[192+i*4+2]=az3; rr[192+i*4+3]=aw3;
    __syncthreads();
    float s = 0.f;
    #pragma unroll
    for (int r = 0; r < 16; ++r) s += red[r][t];
    partials[((size_t)b * CH + ch) * D + t] = s;

    // wave 0: sorted top-64 of this chunk's <=128 candidates
    if (w == 0) {
        u64 A = wave_sort_desc(cand[l], l);
        u64 Bc = wave_sort_desc(cand[64 + l], l);
        u64 rev = __shfl_xor(Bc, 63, 64);
        A = (A > rev) ? A : rev;
        A = wave_merge_desc(A, l);
        lists[((size_t)b * CH + ch) * K + l] = A;
    }
}

// Epilogue per batch: merge 16 sorted top-64 lists -> softmax -> gather ->
// global_latent.
__global__ __launch_bounds__(256) void epilogue_kernel(
        const u64* __restrict__ listsg, const float* __restrict__ latent,
        const float* __restrict__ partials, const float* __restrict__ cnt,
        float* __restrict__ out_mask, float* __restrict__ out_idx,
        float* __restrict__ out_imp, float* __restrict__ out_tok,
        float* __restrict__ out_glob) {
    int b = blockIdx.x, t = threadIdx.x, w = t >> 6, l = t & 63;
    __shared__ u64 lb[CH * K];       // 8 KB
    __shared__ int sortedIdx[K];

    for (int q = 0; q < CH * K / 256; ++q)
        lb[t + 256 * q] = listsg[(size_t)b * CH * K + t + 256 * q];
    __syncthreads();

    if (w == 0) {
        u64 cur = lb[l];
        #pragma unroll
        for (int q = 1; q < CH; ++q) {
            u64 rev = lb[q * K + (63 - l)];
            cur = (cur > rev) ? cur : rev;
            cur = wave_merge_desc(cur, l);
        }
        unsigned int u = (unsigned int)(cur >> 16);
        int pos = 2047 - (int)(cur & 0xFFFFu);
        unsigned int fu = (u & 0x80000000u) ? (u ^ 0x80000000u) : ~u;
        float selv = __uint_as_float(fu);
        bool m = (u != MASKED_KEY);
        float x = m ? selv : -1e9f;
        float mx = x;
        #pragma unroll
        for (int mm = 1; mm <= 32; mm <<= 1) mx = fmaxf(mx, __shfl_xor(mx, mm, 64));
        float e = expf(x - mx);
        float sm = e;
        #pragma unroll
        for (int mm = 1; mm <= 32; mm <<= 1) sm += __shfl_xor(sm, mm, 64);
        out_idx[b * K + l] = (float)pos;
        out_mask[b * K + l] = m ? 1.f : 0.f;
        out_imp[b * K + l] = e / sm;
        sortedIdx[l] = pos;
    }
    __syncthreads();

    for (int r = w; r < K; r += 4) {
        int idx = sortedIdx[r];
        float4 x = ((const float4*)(latent + ((size_t)b * N + idx) * D))[l];
        ((float4*)(out_tok + ((size_t)b * K + r) * D))[l] = x;
    }
    float gs = 0.f;
    #pragma unroll
    for (int c = 0; c < CH; ++c) gs += partials[((size_t)b * CH + c) * D + t];
    out_glob[b * D + t] = gs / cnt[b];
}

extern "C" void kernel_launch(void* const* d_in, const int* in_sizes, int n_in,
                              void* d_out, int out_size, void* d_ws, size_t ws_size,
                              hipStream_t stream) {
    const float* latent = (const float*)d_in[0];
    const void*  maskp  = d_in[1];
    const float* Wq = (const float*)d_in[2];
    const float* bq = (const float*)d_in[3];
    const float* Wk = (const float*)d_in[4];
    const float* bk = (const float*)d_in[5];
    const float* Ws = (const float*)d_in[6];
    const float* bs = (const float*)d_in[7];

    float* ws = (float*)d_ws;
    float* v      = ws + OFF_V;
    float* c2     = ws + OFF_C2;
    float* cnt    = ws + OFF_CNT;
    float* part   = ws + OFF_PART;
    int*   modep  = (int*)(ws + OFF_MODE);
    float* Mhat   = ws + OFF_MHAT;
    float* u0     = ws + OFF_U0;
    float* w2     = ws + OFF_W2;
    float* cst2   = ws + OFF_CST2;
    int*   rowlist = (int*)(ws + OFF_ROWS);
    u64*   lists  = (u64*)(ws + OFF_LISTS);
    float* out = (float*)d_out;

    hipLaunchKernelGGL(prep0_kernel, dim3(D + 1), dim3(256), 0, stream,
                       Wq, bq, Wk, bk, Ws, bs, Mhat, u0, w2, cst2);
    hipLaunchKernelGGL(prep1_kernel, dim3(B), dim3(256), 0, stream,
                       latent, maskp, Mhat, u0, w2, cst2, v, c2, cnt, modep, rowlist);
    hipLaunchKernelGGL(main_kernel, dim3(CH, B), dim3(256), 0, stream,
                       latent, cnt, rowlist, v, c2, part, lists);
    hipLaunchKernelGGL(epilogue_kernel, dim3(B), dim3(256), 0, stream,
                       lists, latent, part, cnt,
                       out + O_MASK, out + O_IDX, out + O_IMP, out + O_TOK, out + O_GLOB);
}